// Round 8
// baseline (74.483 us; speedup 1.0000x reference)
//
#include <hip/hip_runtime.h>

#define A_TOTAL 34000

// Levels (H=W=640): L0 G=160 s=4  a=16  base=0      (25600 anchors, 100 16x16 tiles)
//                   L1 G=80  s=8  a=32  base=25600  ( 6400 anchors,  25 16x16 tiles)
//                   L2 G=40  s=16 a=64  base=32000  ( 1600 anchors,   7 chunks of 256)
//                   L3 G=20  s=32 a=128 base=33600  (  400 anchors,   2 chunks of 256)
// grid.x = 134, grid.y = B. No LDS, no barriers: boxes live in wave registers.
// Epilogue re-reads the single matched box from global (L1-hot) — NO cross-lane
// gather: ds_bpermute data from exec-masked-off lanes is UNDEFINED (round-7 bug).

__device__ __forceinline__ float rdlane(float v, int l) {
    return __int_as_float(__builtin_amdgcn_readlane(__float_as_int(v), l));
}

__global__ __launch_bounds__(256) void multi_anchor_encode_reg(
    const float* __restrict__ boxes,   // [B, 128, 4] yxyx f32
    float* __restrict__ out)           // [B, A_TOTAL, 5] f32
{
    const int b    = blockIdx.y;
    const int t    = threadIdx.x;
    const int bid  = blockIdx.x;
    const int lane = t & 63;

    // ---- Anchor decode + block-uniform conservative tile bounds ----
    int   ia = 0, ja = 0, a_flat = 0;
    float s = 4.f, asize = 16.f;
    bool  valid = true;
    float ty0, ty1, tx0, tx1;

    if (bid < 100) {                       // L0: 16x16 tile
        int ty = bid / 10, tx = bid - ty * 10;
        int i0 = ty * 16, j0 = tx * 16;
        ia = i0 + (t >> 4); ja = j0 + (t & 15);
        s = 4.f; asize = 16.f;
        a_flat = ia * 160 + ja;
        ty0 = (float)(i0 * 4 - 8);  ty1 = (float)((i0 + 15) * 4 + 8);
        tx0 = (float)(j0 * 4 - 8);  tx1 = (float)((j0 + 15) * 4 + 8);
    } else if (bid < 125) {                // L1: 16x16 tile
        int q = bid - 100; int ty = q / 5, tx = q - ty * 5;
        int i0 = ty * 16, j0 = tx * 16;
        ia = i0 + (t >> 4); ja = j0 + (t & 15);
        s = 8.f; asize = 32.f;
        a_flat = 25600 + ia * 80 + ja;
        ty0 = (float)(i0 * 8 - 16); ty1 = (float)((i0 + 15) * 8 + 16);
        tx0 = (float)(j0 * 8 - 16); tx1 = (float)((j0 + 15) * 8 + 16);
    } else if (bid < 132) {                // L2: flat chunks of 256 (y-band cull)
        int c = bid - 125; int k = c * 256 + t;
        valid = (k < 1600); int kk = valid ? k : 0;
        ia = kk / 40; ja = kk - ia * 40;
        s = 16.f; asize = 64.f;
        a_flat = 32000 + kk;
        int klo = c * 256, khi = (klo + 255 < 1599) ? klo + 255 : 1599;
        int ilo = klo / 40, ihi = khi / 40;
        ty0 = (float)(ilo * 16 - 32); ty1 = (float)(ihi * 16 + 32);
        tx0 = -1e30f; tx1 = 1e30f;
    } else {                               // L3: flat chunks of 256 (y-band cull)
        int c = bid - 132; int k = c * 256 + t;
        valid = (k < 400); int kk = valid ? k : 0;
        ia = kk / 20; ja = kk - ia * 20;
        s = 32.f; asize = 128.f;
        a_flat = 33600 + kk;
        int klo = c * 256, khi = (klo + 255 < 399) ? klo + 255 : 399;
        int ilo = klo / 20, ihi = khi / 20;
        ty0 = (float)(ilo * 32 - 64); ty1 = (float)(ihi * 32 + 64);
        tx0 = -1e30f; tx1 = 1e30f;
    }

    // ---- All 128 boxes into this wave's registers (lane l: boxes l, l+64) ----
    const float4* bb = reinterpret_cast<const float4*>(boxes + (size_t)b * 128 * 4);
    float4 vA = bb[lane];                  // x=ymin y=xmin z=ymax w=xmax
    float4 vB = bb[lane + 64];
    float arA = __fmul_rn(__fsub_rn(vA.z, vA.x), __fsub_rn(vA.w, vA.y));
    float arB = __fmul_rn(__fsub_rn(vB.z, vB.x), __fsub_rn(vB.w, vB.y));

    // Per-wave cull (bounds block-uniform -> identical masks in all waves).
    // Conservative >=/<=: a culled box provably has inter==0 with every anchor.
    bool kA = (vA.z >= ty0) && (vA.x <= ty1) && (vA.w >= tx0) && (vA.y <= tx1);
    bool kB = (vB.z >= ty0) && (vB.x <= ty1) && (vB.w >= tx0) && (vB.y <= tx1);
    unsigned long long mA = __ballot(kA);
    unsigned long long mB = __ballot(kB);

    const float half   = asize * 0.5f;     // exact (power of two)
    const float area_a = asize * asize;    // exact
    const float cy = (float)ia * s, cx = (float)ja * s;  // exact ints in f32
    const float ay0 = cy - half, ax0 = cx - half;
    const float ay1 = cy + half, ax1 = cx + half;

    // ---- Ordered survivor walk, zero memory ops, FULL exec (no divergence
    // above). best=0/bi=0 == np.argmax semantics (all-zero row -> 0; else
    // first index of max; j ascends, accept-path rn chain bit-exact vs numpy).
    // Filter: f64 cross-multiply is EXACT (24+24-bit products < 53), so the
    // real-quotient order decides; rounding monotonicity => no false negatives
    // vs numpy's rounded compare; the rounded fdiv confirm on pass keeps the
    // update decision bit-identical to numpy.
    float  best = 0.0f; int bi = 0;
    double bn_d = 0.0,  bd_d = 1.0;

#define WALK(MASKW, LBASE, JBASE, VV, AR)                                     \
    {                                                                         \
        unsigned int m = (unsigned int)__builtin_amdgcn_readfirstlane(MASKW); \
        while (m) {                                                           \
            int l32 = __builtin_ctz(m); m &= m - 1;                           \
            int ln = LBASE + l32;                                             \
            float bx0 = rdlane(VV.x, ln);                                     \
            float bx1 = rdlane(VV.y, ln);                                     \
            float bx2 = rdlane(VV.z, ln);                                     \
            float bx3 = rdlane(VV.w, ln);                                     \
            float sa  = rdlane(AR, ln);                                       \
            float ymin = fmaxf(ay0, bx0);                                     \
            float xmin = fmaxf(ax0, bx1);                                     \
            float ymax = fminf(ay1, bx2);                                     \
            float xmax = fminf(ax1, bx3);                                     \
            float ih   = fmaxf(__fsub_rn(ymax, ymin), 0.0f);                  \
            float iw   = fmaxf(__fsub_rn(xmax, xmin), 0.0f);                  \
            float inter = __fmul_rn(ih, iw);                                  \
            float denom = __fsub_rn(__fadd_rn(area_a, sa), inter);            \
            double inter_d = (double)inter, denom_d = (double)denom;          \
            if (inter_d * bd_d > bn_d * denom_d) {                            \
                float iou = __fdiv_rn(inter, denom);  /* IEEE == numpy f32 */ \
                if (iou > best) { best = iou; bi = JBASE + l32;               \
                                  bn_d = inter_d; bd_d = denom_d; }           \
            }                                                                 \
        }                                                                     \
    }
    WALK((unsigned int)mA,         0,  0, vA, arA)
    WALK((unsigned int)(mA >> 32), 32, 32, vA, arA)
    WALK((unsigned int)mB,         0,  64, vB, arB)
    WALK((unsigned int)(mB >> 32), 32, 96, vB, arB)
#undef WALK

    if (!valid) return;

    // ---- Matched box via direct global load (L1-hot, per-lane, exec-safe) ----
    float4 mbx = bb[bi];
    float mcy = __fmul_rn(__fadd_rn(mbx.x, mbx.z), 0.5f);
    float mcx = __fmul_rn(__fadd_rn(mbx.y, mbx.w), 0.5f);
    float mh  = __fsub_rn(mbx.z, mbx.x);
    float mw  = __fsub_rn(mbx.w, mbx.y);
    float inv = 1.0f / asize;              // exact power of two

    size_t o = ((size_t)b * A_TOTAL + a_flat) * 5;
    out[o + 0] = best;
    out[o + 1] = __fmul_rn(__fsub_rn(mcy, cy), inv);
    out[o + 2] = __fmul_rn(__fsub_rn(mcx, cx), inv);
    out[o + 3] = __fmul_rn(__fsub_rn(mh, asize), inv);
    out[o + 4] = __fmul_rn(__fsub_rn(mw, asize), inv);
}

extern "C" void kernel_launch(void* const* d_in, const int* in_sizes, int n_in,
                              void* d_out, int out_size, void* d_ws, size_t ws_size,
                              hipStream_t stream) {
    const float* boxes = (const float*)d_in[0];
    float* out = (float*)d_out;
    dim3 grid(134, 16 /*B*/);
    multi_anchor_encode_reg<<<grid, 256, 0, stream>>>(boxes, out);
}

// Round 9
// 71.292 us; speedup vs baseline: 1.0448x; 1.0448x over previous
//
#include <hip/hip_runtime.h>

#define A_TOTAL 34000

// Levels (H=W=640): L0 G=160 s=4  a=16  base=0      (25600 anchors, 100 16x16 tiles)
//                   L1 G=80  s=8  a=32  base=25600  ( 6400 anchors,  25 16x16 tiles)
//                   L2 G=40  s=16 a=64  base=32000  ( 1600 anchors,   7 chunks of 256)
//                   L3 G=20  s=32 a=128 base=33600  (  400 anchors,   2 chunks of 256)
// grid.x = 134, grid.y = B.
// Structure: every wave register-loads all 128 boxes + computes identical cull
// ballots (block-uniform bounds). Wave 0 scatter-writes the ORDERED compacted
// survivor list to LDS. One barrier. Walk is a COUNTED loop (unroll 4 -> ILP,
// prefetchable wave-uniform ds_reads) — restoring what made the dense kernel
// hit VALUBusy 90%, at ~6x fewer pairs.

__global__ __launch_bounds__(256) void multi_anchor_encode_v9(
    const float* __restrict__ boxes,   // [B, 128, 4] yxyx f32
    float* __restrict__ out)           // [B, A_TOTAL, 5] f32
{
    __shared__ float4 cbox[128];   // compacted survivors, ascending box order
    __shared__ float  carea[128];

    const int b    = blockIdx.y;
    const int t    = threadIdx.x;
    const int bid  = blockIdx.x;
    const int lane = t & 63;

    // ---- Anchor decode + block-uniform conservative tile bounds ----
    int   ia = 0, ja = 0, a_flat = 0;
    float s = 4.f, asize = 16.f;
    bool  valid = true;
    float ty0, ty1, tx0, tx1;

    if (bid < 100) {                       // L0: 16x16 tile
        int ty = bid / 10, tx = bid - ty * 10;
        int i0 = ty * 16, j0 = tx * 16;
        ia = i0 + (t >> 4); ja = j0 + (t & 15);
        s = 4.f; asize = 16.f;
        a_flat = ia * 160 + ja;
        ty0 = (float)(i0 * 4 - 8);  ty1 = (float)((i0 + 15) * 4 + 8);
        tx0 = (float)(j0 * 4 - 8);  tx1 = (float)((j0 + 15) * 4 + 8);
    } else if (bid < 125) {                // L1: 16x16 tile
        int q = bid - 100; int ty = q / 5, tx = q - ty * 5;
        int i0 = ty * 16, j0 = tx * 16;
        ia = i0 + (t >> 4); ja = j0 + (t & 15);
        s = 8.f; asize = 32.f;
        a_flat = 25600 + ia * 80 + ja;
        ty0 = (float)(i0 * 8 - 16); ty1 = (float)((i0 + 15) * 8 + 16);
        tx0 = (float)(j0 * 8 - 16); tx1 = (float)((j0 + 15) * 8 + 16);
    } else if (bid < 132) {                // L2: flat chunks of 256 (y-band cull)
        int c = bid - 125; int k = c * 256 + t;
        valid = (k < 1600); int kk = valid ? k : 0;
        ia = kk / 40; ja = kk - ia * 40;
        s = 16.f; asize = 64.f;
        a_flat = 32000 + kk;
        int klo = c * 256, khi = (klo + 255 < 1599) ? klo + 255 : 1599;
        int ilo = klo / 40, ihi = khi / 40;
        ty0 = (float)(ilo * 16 - 32); ty1 = (float)(ihi * 16 + 32);
        tx0 = -1e30f; tx1 = 1e30f;
    } else {                               // L3: flat chunks of 256 (y-band cull)
        int c = bid - 132; int k = c * 256 + t;
        valid = (k < 400); int kk = valid ? k : 0;
        ia = kk / 20; ja = kk - ia * 20;
        s = 32.f; asize = 128.f;
        a_flat = 33600 + kk;
        int klo = c * 256, khi = (klo + 255 < 399) ? klo + 255 : 399;
        int ilo = klo / 20, ihi = khi / 20;
        ty0 = (float)(ilo * 32 - 64); ty1 = (float)(ihi * 32 + 64);
        tx0 = -1e30f; tx1 = 1e30f;
    }

    // ---- Every wave: register-load all boxes, identical cull ballots ----
    const float4* bb = reinterpret_cast<const float4*>(boxes + (size_t)b * 128 * 4);
    float4 vA = bb[lane];                  // x=ymin y=xmin z=ymax w=xmax
    float4 vB = bb[lane + 64];
    // Conservative >=/<=: a culled box provably has inter==0 with every anchor.
    bool kA = (vA.z >= ty0) && (vA.x <= ty1) && (vA.w >= tx0) && (vA.y <= tx1);
    bool kB = (vB.z >= ty0) && (vB.x <= ty1) && (vB.w >= tx0) && (vB.y <= tx1);
    unsigned long long mA = __ballot(kA);
    unsigned long long mB = __ballot(kB);
    const int cnt = __popcll(mA) + __popcll(mB);   // same in every wave

    // Wave 0 scatter-writes the ordered compacted list (ballot-prefix pos).
    if (t < 64) {
        unsigned long long below = (1ull << lane) - 1ull;
        if (kA) {
            int p = __popcll(mA & below);
            cbox[p]  = vA;
            carea[p] = __fmul_rn(__fsub_rn(vA.z, vA.x), __fsub_rn(vA.w, vA.y));
        }
        if (kB) {
            int p = __popcll(mA) + __popcll(mB & below);
            cbox[p]  = vB;
            carea[p] = __fmul_rn(__fsub_rn(vB.z, vB.x), __fsub_rn(vB.w, vB.y));
        }
    }
    __syncthreads();                       // the ONLY barrier

    const float half   = asize * 0.5f;     // exact (power of two)
    const float area_a = asize * asize;    // exact
    const float cy = (float)ia * s, cx = (float)ja * s;  // exact ints in f32
    const float ay0 = cy - half, ax0 = cx - half;
    const float ay1 = cy + half, ax1 = cx + half;

    // ---- Counted survivor loop. best=0/bl=0 == np.argmax semantics:
    // all-zero row -> original box 0 (handled in epilogue); else first index
    // of the max — list ascends and the accept-path rn chain is bit-identical
    // to numpy f32. Filter: f64 cross-multiply is EXACT (24+24 < 53 bits);
    // real-quotient order + rounding monotonicity => skips are provably safe;
    // the rounded fdiv confirm keeps the update decision == numpy's.
    float  best = 0.0f; int bl = 0;
    double bn_d = 0.0,  bd_d = 1.0;
    #pragma unroll 4
    for (int m = 0; m < cnt; ++m) {
        float4 v  = cbox[m];               // wave-uniform LDS broadcast
        float  sa = carea[m];
        float ymin = fmaxf(ay0, v.x);
        float xmin = fmaxf(ax0, v.y);
        float ymax = fminf(ay1, v.z);
        float xmax = fminf(ax1, v.w);
        float ih   = fmaxf(__fsub_rn(ymax, ymin), 0.0f);
        float iw   = fmaxf(__fsub_rn(xmax, xmin), 0.0f);
        float inter = __fmul_rn(ih, iw);
        float denom = __fsub_rn(__fadd_rn(area_a, sa), inter);
        double id = (double)inter, dd = (double)denom;
        if (id * bd_d > bn_d * dd) {
            float iou = __fdiv_rn(inter, denom);   // IEEE == numpy f32
            if (iou > best) { best = iou; bl = m; bn_d = id; bd_d = dd; }
        }
    }

    if (!valid) return;

    // ---- Matched box: compacted entry, or original box 0 if all IoU == 0 ----
    float4 mbx;
    if (best > 0.0f) mbx = cbox[bl];       // per-lane ds_read, exec-safe
    else             mbx = bb[0];          // np.argmax of all-zero row -> 0
    float mcy = __fmul_rn(__fadd_rn(mbx.x, mbx.z), 0.5f);
    float mcx = __fmul_rn(__fadd_rn(mbx.y, mbx.w), 0.5f);
    float mh  = __fsub_rn(mbx.z, mbx.x);
    float mw  = __fsub_rn(mbx.w, mbx.y);
    float inv = 1.0f / asize;              // exact power of two

    size_t o = ((size_t)b * A_TOTAL + a_flat) * 5;
    out[o + 0] = best;
    out[o + 1] = __fmul_rn(__fsub_rn(mcy, cy), inv);
    out[o + 2] = __fmul_rn(__fsub_rn(mcx, cx), inv);
    out[o + 3] = __fmul_rn(__fsub_rn(mh, asize), inv);
    out[o + 4] = __fmul_rn(__fsub_rn(mw, asize), inv);
}

extern "C" void kernel_launch(void* const* d_in, const int* in_sizes, int n_in,
                              void* d_out, int out_size, void* d_ws, size_t ws_size,
                              hipStream_t stream) {
    const float* boxes = (const float*)d_in[0];
    float* out = (float*)d_out;
    dim3 grid(134, 16 /*B*/);
    multi_anchor_encode_v9<<<grid, 256, 0, stream>>>(boxes, out);
}